// Round 1
// baseline (153.048 us; speedup 1.0000x reference)
//
#include <hip/hip_runtime.h>
#include <cstdint>

#define TDIM 8192   // B_*S_ = 4*2048 flattened tokens
#define MDIM 1024   // in_features (GEMM K)
#define NDIM 1024   // out_features
#define KBITS 8

typedef __bf16 bf16x8 __attribute__((ext_vector_type(8)));
typedef float f32x4 __attribute__((ext_vector_type(4)));

// address-space casts for global_load_lds (CK-style via uintptr_t)
#define GAS(p) ((__attribute__((address_space(1))) void*)(uintptr_t)(p))
#define LAS(p) ((__attribute__((address_space(3))) void*)(uintptr_t)(p))

__device__ __forceinline__ unsigned short f2bf(float f) {
    union { float f; unsigned u; } v; v.f = f;
    unsigned r = v.u + 0x7fffu + ((v.u >> 16) & 1u);  // round-to-nearest-even
    return (unsigned short)(r >> 16);
}

// ---- kernel 1: x fp32 -> bf16 bits, 8 elems/thread, fully coalesced ----
__global__ __launch_bounds__(256) void prep_x_kernel(const float* __restrict__ x,
                                                     unsigned short* __restrict__ xb) {
    size_t idx = ((size_t)blockIdx.x * 256 + threadIdx.x) * 8;
    float4 a = *(const float4*)(x + idx);
    float4 b = *(const float4*)(x + idx + 4);
    uint4 o;
    o.x = (unsigned)f2bf(a.x) | ((unsigned)f2bf(a.y) << 16);
    o.y = (unsigned)f2bf(a.z) | ((unsigned)f2bf(a.w) << 16);
    o.z = (unsigned)f2bf(b.x) | ((unsigned)f2bf(b.y) << 16);
    o.w = (unsigned)f2bf(b.z) | ((unsigned)f2bf(b.w) << 16);
    *(uint4*)(xb + idx) = o;
}

// ---- kernel 2: Wt[n][m] = bf16( sum_k scale[k][n] * binary[k][m][n] ) ----
// 64x64 tile per block; reads coalesced along n, LDS transpose (+1 pad),
// writes coalesced along m.
__global__ __launch_bounds__(256) void prep_w_kernel(const float* __restrict__ binary,
                                                     const float* __restrict__ scale,
                                                     unsigned short* __restrict__ wtr) {
    __shared__ float tile[64][65];
    const int tid = threadIdx.x;
    const int n0 = blockIdx.x * 64;
    const int m0 = blockIdx.y * 64;
    float acc[16];
#pragma unroll
    for (int i = 0; i < 16; ++i) acc[i] = 0.f;
    for (int k = 0; k < KBITS; ++k) {
        const float* bk = binary + ((size_t)k * MDIM + m0) * NDIM + n0;
        const float* sk = scale + (size_t)k * NDIM + n0;
#pragma unroll
        for (int i = 0; i < 16; ++i) {
            int e = tid + i * 256;
            int r = e >> 6, c = e & 63;               // r = m offset, c = n offset
            acc[i] += sk[c] * bk[(size_t)r * NDIM + c];
        }
    }
#pragma unroll
    for (int i = 0; i < 16; ++i) {
        int e = tid + i * 256;
        tile[e & 63][e >> 6] = acc[i];                // tile[n][m]
    }
    __syncthreads();
#pragma unroll
    for (int i = 0; i < 16; ++i) {
        int e = tid + i * 256;
        int rn = e >> 6, cm = e & 63;
        wtr[(size_t)(n0 + rn) * MDIM + m0 + cm] = f2bf(tile[rn][cm]);
    }
}

// ---- kernel 3: out[t][n] = sum_m xb[t][m]*Wt[n][m] + bias[n] ----
// 128x128 tile, BK=32, 4 waves in 2x2, each wave 64x64 via 4x4 MFMA 16x16x32.
// global_load_lds width=16 staging; XOR granule swizzle applied to the GLOBAL
// source (LDS dest stays base+lane*16 contiguous as HW requires) so that
// ds_read_b128 frag loads tile all 32 banks evenly.
__global__ __launch_bounds__(256) void gemm_kernel(const unsigned short* __restrict__ xb,
                                                   const unsigned short* __restrict__ wtr,
                                                   const float* __restrict__ bias,
                                                   float* __restrict__ out) {
    __shared__ __attribute__((aligned(16))) unsigned short sA[128 * 32];
    __shared__ __attribute__((aligned(16))) unsigned short sB[128 * 32];

    const int tid = threadIdx.x;
    const int lane = tid & 63;
    const int wv = tid >> 6;
    const int wrow = wv >> 1;   // wave tile row (t), 0..1
    const int wcol = wv & 1;    // wave tile col (n), 0..1
    const int lrow = lane & 15;
    const int q = lane >> 4;    // quad id 0..3 -> k-granule

    const int n0 = blockIdx.x * 128;
    const int t0 = blockIdx.y * 128;

    // staging: 512 granules (16B) per tile, 2 per thread; LDS slot s holds
    // global granule ((s&3)^(row&3)) of row s>>2.
    const int s1 = tid, s2 = tid + 256;
    const int r1 = s1 >> 2, g1 = (s1 & 3) ^ (r1 & 3);
    const int r2 = s2 >> 2, g2 = (s2 & 3) ^ (r2 & 3);

    const unsigned short* a1 = xb + (size_t)(t0 + r1) * MDIM + g1 * 8;
    const unsigned short* a2 = xb + (size_t)(t0 + r2) * MDIM + g2 * 8;
    const unsigned short* b1 = wtr + (size_t)(n0 + r1) * MDIM + g1 * 8;
    const unsigned short* b2 = wtr + (size_t)(n0 + r2) * MDIM + g2 * 8;
    unsigned short* da1 = sA + s1 * 8;
    unsigned short* da2 = sA + s2 * 8;
    unsigned short* db1 = sB + s1 * 8;
    unsigned short* db2 = sB + s2 * 8;

    // fragment LDS offsets (ushort units): row m, swizzled granule q^(m&3)
    int a_off[4], b_off[4];
#pragma unroll
    for (int i = 0; i < 4; ++i) {
        int m = wrow * 64 + i * 16 + lrow;
        a_off[i] = (m * 4 + (q ^ (m & 3))) * 8;
        int n = wcol * 64 + i * 16 + lrow;
        b_off[i] = (n * 4 + (q ^ (n & 3))) * 8;
    }

    f32x4 acc[4][4];
    const f32x4 zero = {0.f, 0.f, 0.f, 0.f};
#pragma unroll
    for (int i = 0; i < 4; ++i)
#pragma unroll
        for (int j = 0; j < 4; ++j) acc[i][j] = zero;

    for (int k0 = 0; k0 < MDIM; k0 += 32) {
        __builtin_amdgcn_global_load_lds(GAS(a1 + k0), LAS(da1), 16, 0, 0);
        __builtin_amdgcn_global_load_lds(GAS(a2 + k0), LAS(da2), 16, 0, 0);
        __builtin_amdgcn_global_load_lds(GAS(b1 + k0), LAS(db1), 16, 0, 0);
        __builtin_amdgcn_global_load_lds(GAS(b2 + k0), LAS(db2), 16, 0, 0);
        __syncthreads();   // compiler emits vmcnt(0) drain before s_barrier

        bf16x8 af[4], bfr[4];
#pragma unroll
        for (int i = 0; i < 4; ++i) af[i] = *(const bf16x8*)(sA + a_off[i]);
#pragma unroll
        for (int i = 0; i < 4; ++i) bfr[i] = *(const bf16x8*)(sB + b_off[i]);

#pragma unroll
        for (int i = 0; i < 4; ++i)
#pragma unroll
            for (int j = 0; j < 4; ++j)
                acc[i][j] = __builtin_amdgcn_mfma_f32_16x16x32_bf16(af[i], bfr[j],
                                                                    acc[i][j], 0, 0, 0);
        __syncthreads();   // protect single LDS buffer before restage
    }

    // epilogue: C/D layout col=lane&15 (n), row=q*4+reg (t). fuse bias.
#pragma unroll
    for (int j = 0; j < 4; ++j) {
        const int n = n0 + wcol * 64 + j * 16 + lrow;
        const float bv = bias[n];
#pragma unroll
        for (int i = 0; i < 4; ++i) {
            const int tb = t0 + wrow * 64 + i * 16 + q * 4;
#pragma unroll
            for (int r = 0; r < 4; ++r) {
                out[(size_t)(tb + r) * NDIM + n] = acc[i][j][r] + bv;
            }
        }
    }
}

extern "C" void kernel_launch(void* const* d_in, const int* in_sizes, int n_in,
                              void* d_out, int out_size, void* d_ws, size_t ws_size,
                              hipStream_t stream) {
    const float* x      = (const float*)d_in[0];   // [4,2048,1024] fp32
    const float* binary = (const float*)d_in[1];   // [8,1024,1024] fp32 (+/-1)
    const float* scale  = (const float*)d_in[2];   // [8,1,1024] fp32
    const float* bias   = (const float*)d_in[3];   // [1024] fp32
    float* out = (float*)d_out;                    // [4,2048,1024] fp32

    unsigned short* xb  = (unsigned short*)d_ws;                    // 16 MB bf16 x
    unsigned short* wtr = xb + (size_t)TDIM * MDIM;                 // 2 MB bf16 Wt[n][m]

    prep_x_kernel<<<(TDIM * MDIM) / (256 * 8), 256, 0, stream>>>(x, xb);
    prep_w_kernel<<<dim3(NDIM / 64, MDIM / 64), 256, 0, stream>>>(binary, scale, wtr);
    gemm_kernel<<<dim3(NDIM / 128, TDIM / 128), 256, 0, stream>>>(xb, wtr, bias, out);
}

// Round 2
// 151.651 us; speedup vs baseline: 1.0092x; 1.0092x over previous
//
#include <hip/hip_runtime.h>
#include <cstdint>

#define TDIM 8192   // B_*S_ = 4*2048 flattened tokens
#define MDIM 1024   // in_features (GEMM K)
#define NDIM 1024   // out_features
#define KBITS 8
#define BK 64       // K-depth per staging iteration (32 MFMA per barrier pair)

typedef __bf16 bf16x8 __attribute__((ext_vector_type(8)));
typedef float f32x4 __attribute__((ext_vector_type(4)));

#define GAS(p) ((__attribute__((address_space(1))) void*)(uintptr_t)(p))
#define LAS(p) ((__attribute__((address_space(3))) void*)(uintptr_t)(p))

__device__ __forceinline__ unsigned short f2bf(float f) {
    union { float f; unsigned u; } v; v.f = f;
    unsigned r = v.u + 0x7fffu + ((v.u >> 16) & 1u);  // round-to-nearest-even
    return (unsigned short)(r >> 16);
}

// ---- fused prep: blocks [0,4096) cast x fp32->bf16; blocks [4096,4352)
// fold W: Wt[n][m] = bf16( sum_k scale[k][n] * binary[k][m][n] ) ----
__global__ __launch_bounds__(256) void prep_kernel(const float* __restrict__ x,
                                                   unsigned short* __restrict__ xb,
                                                   const float* __restrict__ binary,
                                                   const float* __restrict__ scale,
                                                   unsigned short* __restrict__ wtr) {
    __shared__ float tile[64][65];
    const int tid = threadIdx.x;
    if (blockIdx.x < 4096) {
        // ---- x cast: 8 floats/thread, fully coalesced ----
        size_t idx = ((size_t)blockIdx.x * 256 + tid) * 8;
        float4 a = *(const float4*)(x + idx);
        float4 b = *(const float4*)(x + idx + 4);
        uint4 o;
        o.x = (unsigned)f2bf(a.x) | ((unsigned)f2bf(a.y) << 16);
        o.y = (unsigned)f2bf(a.z) | ((unsigned)f2bf(a.w) << 16);
        o.z = (unsigned)f2bf(b.x) | ((unsigned)f2bf(b.y) << 16);
        o.w = (unsigned)f2bf(b.z) | ((unsigned)f2bf(b.w) << 16);
        *(uint4*)(xb + idx) = o;
        return;
    }
    // ---- W fold, 64x64 tile: thread owns one m-row r, 16 consecutive n ----
    const int b2 = blockIdx.x - 4096;
    const int n0 = (b2 & 15) * 64;
    const int m0 = (b2 >> 4) * 64;
    const int r = tid >> 2;          // m offset 0..63
    const int sub = tid & 3;         // 16-wide n chunk
    f32x4 acc4[4];
#pragma unroll
    for (int j = 0; j < 4; ++j) acc4[j] = (f32x4){0.f, 0.f, 0.f, 0.f};
    for (int k = 0; k < KBITS; ++k) {
        const float* bk = binary + ((size_t)k * MDIM + m0 + r) * NDIM + n0 + sub * 16;
        const float* sk = scale + (size_t)k * NDIM + n0 + sub * 16;
#pragma unroll
        for (int j = 0; j < 4; ++j) {
            f32x4 v = *(const f32x4*)(bk + j * 4);
            f32x4 s = *(const f32x4*)(sk + j * 4);
            acc4[j] += v * s;
        }
    }
    // transpose through LDS: tile[n][m]
#pragma unroll
    for (int j = 0; j < 4; ++j)
#pragma unroll
        for (int e = 0; e < 4; ++e) tile[sub * 16 + j * 4 + e][r] = acc4[j][e];
    __syncthreads();
    // write Wt[n][m] bf16, coalesced along m
    const int rn = tid >> 2;
    const int cs = (tid & 3) * 16;
    unsigned short ob[16];
#pragma unroll
    for (int e = 0; e < 16; ++e) ob[e] = f2bf(tile[rn][cs + e]);
    unsigned short* dst = wtr + (size_t)(n0 + rn) * MDIM + m0 + cs;
#pragma unroll
    for (int j = 0; j < 4; ++j) *(ushort4*)(dst + j * 4) = *(ushort4*)(ob + j * 4);
}

// ---- gemm: out[t][n] = sum_m xb[t][m]*Wt[n][m] + bias[n] ----
// 128x128 tile, BK=64, 4 waves 2x2, wave = 64x64 via 4x4 MFMA 16x16x32 (x2 k-halves).
// grid (t=64, n=8): consecutive blocks share n-strip per XCD -> L2-resident B + A strip.
__global__ __launch_bounds__(256) void gemm_kernel(const unsigned short* __restrict__ xb,
                                                   const unsigned short* __restrict__ wtr,
                                                   const float* __restrict__ bias,
                                                   float* __restrict__ out) {
    __shared__ __attribute__((aligned(16))) unsigned short sA[128 * BK];
    __shared__ __attribute__((aligned(16))) unsigned short sB[128 * BK];

    const int tid = threadIdx.x;
    const int lane = tid & 63;
    const int wv = tid >> 6;
    const int wrow = wv >> 1;
    const int wcol = wv & 1;
    const int lrow = lane & 15;
    const int q = lane >> 4;

    const int t0 = blockIdx.x * 128;
    const int n0 = blockIdx.y * 128;

    // staging: 1024 granules (16B) per tile, 4/thread. LDS slot s = r*8+gs holds
    // global granule gs^(r&7) of row r (XOR swizzle so frag reads hit all banks).
    const unsigned short* srcA[4];
    const unsigned short* srcB[4];
    unsigned short* dstA[4];
    unsigned short* dstB[4];
#pragma unroll
    for (int j = 0; j < 4; ++j) {
        int s = tid + j * 256;
        int r = s >> 3;
        int g = (s & 7) ^ (r & 7);
        srcA[j] = xb + (size_t)(t0 + r) * MDIM + g * 8;
        srcB[j] = wtr + (size_t)(n0 + r) * MDIM + g * 8;
        dstA[j] = sA + s * 8;
        dstB[j] = sB + s * 8;
    }

    // fragment LDS offsets: row m, k-half h, granule (h*4+q)^(m&7)
    int a_off[2][4], b_off[2][4];
#pragma unroll
    for (int h = 0; h < 2; ++h)
#pragma unroll
        for (int i = 0; i < 4; ++i) {
            int m = wrow * 64 + i * 16 + lrow;
            a_off[h][i] = (m * 8 + ((h * 4 + q) ^ (m & 7))) * 8;
            int n = wcol * 64 + i * 16 + lrow;
            b_off[h][i] = (n * 8 + ((h * 4 + q) ^ (n & 7))) * 8;
        }

    f32x4 acc[4][4];
    const f32x4 zero = {0.f, 0.f, 0.f, 0.f};
#pragma unroll
    for (int i = 0; i < 4; ++i)
#pragma unroll
        for (int j = 0; j < 4; ++j) acc[i][j] = zero;

    for (int k0 = 0; k0 < MDIM; k0 += BK) {
#pragma unroll
        for (int j = 0; j < 4; ++j)
            __builtin_amdgcn_global_load_lds(GAS(srcA[j] + k0), LAS(dstA[j]), 16, 0, 0);
#pragma unroll
        for (int j = 0; j < 4; ++j)
            __builtin_amdgcn_global_load_lds(GAS(srcB[j] + k0), LAS(dstB[j]), 16, 0, 0);
        __syncthreads();

#pragma unroll
        for (int h = 0; h < 2; ++h) {
            bf16x8 af[4], bfr[4];
#pragma unroll
            for (int i = 0; i < 4; ++i) af[i] = *(const bf16x8*)(sA + a_off[h][i]);
#pragma unroll
            for (int i = 0; i < 4; ++i) bfr[i] = *(const bf16x8*)(sB + b_off[h][i]);
#pragma unroll
            for (int i = 0; i < 4; ++i)
#pragma unroll
                for (int j = 0; j < 4; ++j)
                    acc[i][j] = __builtin_amdgcn_mfma_f32_16x16x32_bf16(af[i], bfr[j],
                                                                        acc[i][j], 0, 0, 0);
        }
        __syncthreads();
    }

    // epilogue: C/D layout col=lane&15 (n), row=q*4+reg (t). fuse bias.
#pragma unroll
    for (int j = 0; j < 4; ++j) {
        const int n = n0 + wcol * 64 + j * 16 + lrow;
        const float bv = bias[n];
#pragma unroll
        for (int i = 0; i < 4; ++i) {
            const int tb = t0 + wrow * 64 + i * 16 + q * 4;
#pragma unroll
            for (int r = 0; r < 4; ++r) {
                out[(size_t)(tb + r) * NDIM + n] = acc[i][j][r] + bv;
            }
        }
    }
}

extern "C" void kernel_launch(void* const* d_in, const int* in_sizes, int n_in,
                              void* d_out, int out_size, void* d_ws, size_t ws_size,
                              hipStream_t stream) {
    const float* x      = (const float*)d_in[0];   // [4,2048,1024] fp32
    const float* binary = (const float*)d_in[1];   // [8,1024,1024] fp32 (+/-1)
    const float* scale  = (const float*)d_in[2];   // [8,1,1024] fp32
    const float* bias   = (const float*)d_in[3];   // [1024] fp32
    float* out = (float*)d_out;                    // [4,2048,1024] fp32

    unsigned short* xb  = (unsigned short*)d_ws;            // 16 MB bf16 x
    unsigned short* wtr = xb + (size_t)TDIM * MDIM;         // 2 MB bf16 Wt[n][m]

    prep_kernel<<<4096 + 256, 256, 0, stream>>>(x, xb, binary, scale, wtr);
    gemm_kernel<<<dim3(TDIM / 128, NDIM / 128), 256, 0, stream>>>(xb, wtr, bias, out);
}

// Round 3
// 127.095 us; speedup vs baseline: 1.2042x; 1.1932x over previous
//
#include <hip/hip_runtime.h>
#include <cstdint>

#define TDIM 8192   // B_*S_ = 4*2048 flattened tokens
#define MDIM 1024   // in_features (GEMM K)
#define NDIM 1024   // out_features
#define KBITS 8
#define BK 64       // K-depth per staging iteration (32 MFMA per barrier pair)

typedef __bf16 bf16x8 __attribute__((ext_vector_type(8)));
typedef float f32x4 __attribute__((ext_vector_type(4)));

#define GAS(p) ((__attribute__((address_space(1))) void*)(uintptr_t)(p))
#define LAS(p) ((__attribute__((address_space(3))) void*)(uintptr_t)(p))

__device__ __forceinline__ unsigned short f2bf(float f) {
    union { float f; unsigned u; } v; v.f = f;
    unsigned r = v.u + 0x7fffu + ((v.u >> 16) & 1u);  // round-to-nearest-even
    return (unsigned short)(r >> 16);
}

// ---- fused prep ----
// blocks [0,1024): W-fold 32x32 tiles (dispatched FIRST so no serial tail):
//   Wt[n][m] = bf16( sum_k scale[k][n] * binary[k][m][n] ), k fully unrolled
//   so all 8 binary loads are in flight at once (latency-bound otherwise).
// blocks [1024,5120): x fp32 -> bf16 cast, 8 elems/thread, coalesced.
__global__ __launch_bounds__(256) void prep_kernel(const float* __restrict__ x,
                                                   unsigned short* __restrict__ xb,
                                                   const float* __restrict__ binary,
                                                   const float* __restrict__ scale,
                                                   unsigned short* __restrict__ wtr) {
    __shared__ float tile[32][33];
    const int tid = threadIdx.x;
    if (blockIdx.x >= 1024) {
        size_t idx = ((size_t)(blockIdx.x - 1024) * 256 + tid) * 8;
        float4 a = *(const float4*)(x + idx);
        float4 b = *(const float4*)(x + idx + 4);
        uint4 o;
        o.x = (unsigned)f2bf(a.x) | ((unsigned)f2bf(a.y) << 16);
        o.y = (unsigned)f2bf(a.z) | ((unsigned)f2bf(a.w) << 16);
        o.z = (unsigned)f2bf(b.x) | ((unsigned)f2bf(b.y) << 16);
        o.w = (unsigned)f2bf(b.z) | ((unsigned)f2bf(b.w) << 16);
        *(uint4*)(xb + idx) = o;
        return;
    }
    // ---- W-fold: 32x32 tile, thread owns (m-row r, 4 consecutive n) ----
    const int n0 = (blockIdx.x & 31) * 32;
    const int m0 = (blockIdx.x >> 5) * 32;
    const int r = tid >> 3;          // m offset 0..31
    const int cn = (tid & 7) * 4;    // n offset 0..28 step 4
    f32x4 acc = {0.f, 0.f, 0.f, 0.f};
#pragma unroll
    for (int k = 0; k < KBITS; ++k) {
        f32x4 v = *(const f32x4*)(binary + ((size_t)k * MDIM + m0 + r) * NDIM + n0 + cn);
        f32x4 s = *(const f32x4*)(scale + (size_t)k * NDIM + n0 + cn);
        acc += v * s;
    }
    // transpose through LDS: tile[n][m]
#pragma unroll
    for (int e = 0; e < 4; ++e) tile[cn + e][r] = acc[e];
    __syncthreads();
    // write Wt[n][m] bf16, coalesced along m (8B/thread, 64B/row-segment)
    const int rn = tid >> 3;
    const int cm = (tid & 7) * 4;
    ushort4 o4;
    o4.x = f2bf(tile[rn][cm + 0]);
    o4.y = f2bf(tile[rn][cm + 1]);
    o4.z = f2bf(tile[rn][cm + 2]);
    o4.w = f2bf(tile[rn][cm + 3]);
    *(ushort4*)(wtr + (size_t)(n0 + rn) * MDIM + m0 + cm) = o4;
}

// ---- gemm: out[t][n] = sum_m xb[t][m]*Wt[n][m] + bias[n] ----
// 128x128 tile, BK=64, 4 waves 2x2, wave = 64x64 via 4x4 MFMA 16x16x32 (x2 k-halves).
// grid (t=64, n=8): block i -> XCD i%8 and 64%8==0, so each XCD keeps the same
// A-row strip across all n-columns -> A stays L2-resident (~16 MB total fetch).
__global__ __launch_bounds__(256) void gemm_kernel(const unsigned short* __restrict__ xb,
                                                   const unsigned short* __restrict__ wtr,
                                                   const float* __restrict__ bias,
                                                   float* __restrict__ out) {
    __shared__ __attribute__((aligned(16))) unsigned short sA[128 * BK];
    __shared__ __attribute__((aligned(16))) unsigned short sB[128 * BK];

    const int tid = threadIdx.x;
    const int lane = tid & 63;
    const int wv = tid >> 6;
    const int wrow = wv >> 1;
    const int wcol = wv & 1;
    const int lrow = lane & 15;
    const int q = lane >> 4;

    const int t0 = blockIdx.x * 128;
    const int n0 = blockIdx.y * 128;

    // staging: 1024 granules (16B) per tile, 4/thread. LDS slot s = r*8+gs holds
    // global granule gs^(r&7) of row r (XOR swizzle so frag reads hit all banks).
    const unsigned short* srcA[4];
    const unsigned short* srcB[4];
    unsigned short* dstA[4];
    unsigned short* dstB[4];
#pragma unroll
    for (int j = 0; j < 4; ++j) {
        int s = tid + j * 256;
        int r = s >> 3;
        int g = (s & 7) ^ (r & 7);
        srcA[j] = xb + (size_t)(t0 + r) * MDIM + g * 8;
        srcB[j] = wtr + (size_t)(n0 + r) * MDIM + g * 8;
        dstA[j] = sA + s * 8;
        dstB[j] = sB + s * 8;
    }

    // fragment LDS offsets: row m, k-half h, granule (h*4+q)^(m&7)
    int a_off[2][4], b_off[2][4];
#pragma unroll
    for (int h = 0; h < 2; ++h)
#pragma unroll
        for (int i = 0; i < 4; ++i) {
            int m = wrow * 64 + i * 16 + lrow;
            a_off[h][i] = (m * 8 + ((h * 4 + q) ^ (m & 7))) * 8;
            int n = wcol * 64 + i * 16 + lrow;
            b_off[h][i] = (n * 8 + ((h * 4 + q) ^ (n & 7))) * 8;
        }

    f32x4 acc[4][4];
    const f32x4 zero = {0.f, 0.f, 0.f, 0.f};
#pragma unroll
    for (int i = 0; i < 4; ++i)
#pragma unroll
        for (int j = 0; j < 4; ++j) acc[i][j] = zero;

    for (int k0 = 0; k0 < MDIM; k0 += BK) {
#pragma unroll
        for (int j = 0; j < 4; ++j)
            __builtin_amdgcn_global_load_lds(GAS(srcA[j] + k0), LAS(dstA[j]), 16, 0, 0);
#pragma unroll
        for (int j = 0; j < 4; ++j)
            __builtin_amdgcn_global_load_lds(GAS(srcB[j] + k0), LAS(dstB[j]), 16, 0, 0);
        __syncthreads();

#pragma unroll
        for (int h = 0; h < 2; ++h) {
            bf16x8 af[4], bfr[4];
#pragma unroll
            for (int i = 0; i < 4; ++i) af[i] = *(const bf16x8*)(sA + a_off[h][i]);
#pragma unroll
            for (int i = 0; i < 4; ++i) bfr[i] = *(const bf16x8*)(sB + b_off[h][i]);
#pragma unroll
            for (int i = 0; i < 4; ++i)
#pragma unroll
                for (int j = 0; j < 4; ++j)
                    acc[i][j] = __builtin_amdgcn_mfma_f32_16x16x32_bf16(af[i], bfr[j],
                                                                        acc[i][j], 0, 0, 0);
        }
        __syncthreads();
    }

    // epilogue: C/D layout col=lane&15 (n), row=q*4+reg (t). fuse bias.
#pragma unroll
    for (int j = 0; j < 4; ++j) {
        const int n = n0 + wcol * 64 + j * 16 + lrow;
        const float bv = bias[n];
#pragma unroll
        for (int i = 0; i < 4; ++i) {
            const int tb = t0 + wrow * 64 + i * 16 + q * 4;
#pragma unroll
            for (int r = 0; r < 4; ++r) {
                out[(size_t)(tb + r) * NDIM + n] = acc[i][j][r] + bv;
            }
        }
    }
}

extern "C" void kernel_launch(void* const* d_in, const int* in_sizes, int n_in,
                              void* d_out, int out_size, void* d_ws, size_t ws_size,
                              hipStream_t stream) {
    const float* x      = (const float*)d_in[0];   // [4,2048,1024] fp32
    const float* binary = (const float*)d_in[1];   // [8,1024,1024] fp32 (+/-1)
    const float* scale  = (const float*)d_in[2];   // [8,1,1024] fp32
    const float* bias   = (const float*)d_in[3];   // [1024] fp32
    float* out = (float*)d_out;                    // [4,2048,1024] fp32

    unsigned short* xb  = (unsigned short*)d_ws;            // 16 MB bf16 x
    unsigned short* wtr = xb + (size_t)TDIM * MDIM;         // 2 MB bf16 Wt[n][m]

    prep_kernel<<<1024 + 4096, 256, 0, stream>>>(x, xb, binary, scale, wtr);
    gemm_kernel<<<dim3(TDIM / 128, NDIM / 128), 256, 0, stream>>>(xb, wtr, bias, out);
}